// Round 14
// baseline (109.855 us; speedup 1.0000x reference)
//
#include <hip/hip_runtime.h>
#include <stdint.h>

// HashedInterpolator R13: R9 front-end (FB=64 fine sort, proven contention
// profile) + Morton fine-bin order so consecutive groups of 8 fine bins form
// one 16^3 superregion + R12's S=16 K4 (78.6KB LDS corner staging).
// Pipeline: K1 hist64 -> K2 scan64 -> K3 bucket scatter (+Morton key) ->
// fineA (64-bin chist) -> fineB (cbase+sstart) -> fineC (sorted2) ->
// K4 block-per-16^3-superregion (4913 LDS corners), scatter to out[orig].

#define HASH_MASK 0x3FFFFFu
#define P1 19349663u
#define P2 83492791u
#define NBUCK 64
#define CHUNKS 16
#define FB 64                     // fine bins per bucket (S=8 regions, Morton)
#define NSUP16 512                // 16^3 superregions = groups of 8 fine bins
#define NCORN 4913                // 17^3 corners per superregion
#define PPT 16
#define K3_BLOCK 256
#define PPB (K3_BLOCK * PPT)      // 4096 points per block
#define CMAX 2560                 // max chunk size staged in fineC (40KB LDS)

__device__ __forceinline__ uint32_t bucket_of(float px, float py, float pz) {
    uint32_t bx = ((uint32_t)(int)floorf(px * 128.0f)) >> 5;
    uint32_t by = ((uint32_t)(int)floorf(py * 128.0f)) >> 5;
    uint32_t bz = ((uint32_t)(int)floorf(pz * 128.0f)) >> 5;
    return (bx << 4) | (by << 2) | bz;
}

// fine bin within bucket, MORTON order over (fx,fy,fz) in [0,3]^3:
// bit5..0 = fx1 fy1 fz1 fx0 fy0 fz0  -> group g=f>>3 is the 2x2x2 super coord
__device__ __forceinline__ uint32_t fine_of(float px, float py, float pz) {
    uint32_t fx = (((uint32_t)(int)floorf(px * 128.0f)) >> 3) & 3u;
    uint32_t fy = (((uint32_t)(int)floorf(py * 128.0f)) >> 3) & 3u;
    uint32_t fz = (((uint32_t)(int)floorf(pz * 128.0f)) >> 3) & 3u;
    return ((fx & 1u) << 2) | ((fy & 1u) << 1) | (fz & 1u) |
           ((fx & 2u) << 4) | ((fy & 2u) << 3) | ((fz & 2u) << 2);
}

__device__ __forceinline__ float4 interp_point(float px, float py, float pz,
                                               const float* __restrict__ table) {
    int lx = (int)floorf(px * 128.0f);
    int ly = (int)floorf(py * 128.0f);
    int lz = (int)floorf(pz * 128.0f);
    const float inv = 1.0f / 128.0f;
    float w0x = (px - (float)lx * inv) * 128.0f;
    float w1x = ((float)(lx + 1) * inv - px) * 128.0f;
    float w0y = (py - (float)ly * inv) * 128.0f;
    float w1y = ((float)(ly + 1) * inv - py) * 128.0f;
    float w0z = (pz - (float)lz * inv) * 128.0f;
    float w1z = ((float)(lz + 1) * inv - pz) * 128.0f;
    uint32_t hx0 = (uint32_t)lx, hx1 = (uint32_t)(lx + 1);
    uint32_t hy0 = (uint32_t)ly * P1, hy1 = (uint32_t)(ly + 1) * P1;
    uint32_t hz0 = (uint32_t)lz * P2, hz1 = (uint32_t)(lz + 1) * P2;
    float acc0 = 0.f, acc1 = 0.f, acc2 = 0.f, acc3 = 0.f;
#pragma unroll
    for (int c = 0; c < 8; ++c) {
        int bx = (c >> 2) & 1, by = (c >> 1) & 1, bz = c & 1;
        uint32_t h = ((bx ? hx1 : hx0) ^ (by ? hy1 : hy0) ^ (bz ? hz1 : hz0)) & HASH_MASK;
        const float4 v = *reinterpret_cast<const float4*>(table + (size_t)h * 4);
        float w = ((bx ? w1x : w0x) * (by ? w1y : w0y)) * (bz ? w1z : w0z);
        acc0 += v.x * w; acc1 += v.y * w; acc2 += v.z * w; acc3 += v.w * w;
    }
    return make_float4(acc0, acc1, acc2, acc3);
}

// ---- K1: per-block LDS histogram (64 bins) ----
__global__ __launch_bounds__(K3_BLOCK) void hist_kernel(
    const float* __restrict__ pos, uint32_t* __restrict__ hist, int batch)
{
    __shared__ uint32_t h[NBUCK];
    int tid = threadIdx.x;
    size_t start = (size_t)blockIdx.x * PPB;
    if (tid < NBUCK) h[tid] = 0;
    __syncthreads();
#pragma unroll
    for (int k = 0; k < PPT; ++k) {
        size_t i = start + (size_t)k * K3_BLOCK + tid;
        if (i < (size_t)batch) {
            float px = pos[3 * i + 0];
            float py = pos[3 * i + 1];
            float pz = pos[3 * i + 2];
            atomicAdd(&h[bucket_of(px, py, pz)], 1u);
        }
    }
    __syncthreads();
    if (tid < NBUCK && h[tid]) atomicAdd(&hist[tid], h[tid]);
}

// ---- K2: 64-bin exclusive scan ----
__global__ __launch_bounds__(64) void scan_kernel(
    const uint32_t* __restrict__ hist, uint32_t* __restrict__ cursor)
{
    int t = threadIdx.x;
    uint32_t v = hist[t];
    uint32_t inc = v;
    for (int off = 1; off < 64; off <<= 1) {
        uint32_t n = __shfl_up(inc, off);
        if (t >= off) inc += n;
    }
    cursor[t] = inc - v;
}

// ---- K3: LDS-staged coarse scatter (coalesced) + Morton key emission ----
// After this kernel cursor[b] == inclusive end offset of bucket b.
__global__ __launch_bounds__(K3_BLOCK) void scatter_kernel(
    const float* __restrict__ pos, uint32_t* __restrict__ cursor,
    float4* __restrict__ sorted, uint8_t* __restrict__ key, int batch)
{
    __shared__ float4 staged[PPB];
    __shared__ uint32_t h[NBUCK], lbase[NBUCK], gbase[NBUCK], lcur[NBUCK];
    int tid = threadIdx.x;
    size_t start = (size_t)blockIdx.x * PPB;

    if (tid < NBUCK) h[tid] = 0;
    __syncthreads();

    float px[PPT], py[PPT], pz[PPT];
    uint32_t bb[PPT];
#pragma unroll
    for (int k = 0; k < PPT; ++k) {
        size_t i = start + (size_t)k * K3_BLOCK + tid;
        px[k] = pos[3 * i + 0];
        py[k] = pos[3 * i + 1];
        pz[k] = pos[3 * i + 2];
        bb[k] = bucket_of(px[k], py[k], pz[k]);
        atomicAdd(&h[bb[k]], 1u);
    }
    __syncthreads();

    if (tid < NBUCK) {
        uint32_t v = h[tid];
        uint32_t inc = v;
        for (int off = 1; off < 64; off <<= 1) {
            uint32_t n = __shfl_up(inc, off);
            if (tid >= off) inc += n;
        }
        uint32_t excl = inc - v;
        lbase[tid] = excl;
        lcur[tid] = excl;
        gbase[tid] = atomicAdd(&cursor[tid], v);
    }
    __syncthreads();

#pragma unroll
    for (int k = 0; k < PPT; ++k) {
        size_t i = start + (size_t)k * K3_BLOCK + tid;
        uint32_t slot = atomicAdd(&lcur[bb[k]], 1u);
        staged[slot] = make_float4(px[k], py[k], pz[k], __uint_as_float((uint32_t)i));
    }
    __syncthreads();

#pragma unroll
    for (int k = 0; k < PPT; ++k) {
        int j = k * K3_BLOCK + tid;
        float4 s = staged[j];
        uint32_t b = bucket_of(s.x, s.y, s.z);
        uint32_t slot = gbase[b] + ((uint32_t)j - lbase[b]);
        sorted[slot] = s;
        key[slot] = (uint8_t)fine_of(s.x, s.y, s.z);
    }
}

// ---- fineA: per (bucket,chunk) 64-bin histogram from key bytes ----
__global__ __launch_bounds__(256) void fineA_kernel(
    const uint8_t* __restrict__ key, const uint32_t* __restrict__ cursor,
    uint32_t* __restrict__ chist)
{
    __shared__ uint32_t h[FB];
    int tid = threadIdx.x;
    int b = blockIdx.x >> 4, c = blockIdx.x & (CHUNKS - 1);
    uint32_t bs = b ? cursor[b - 1] : 0u;
    uint32_t be = cursor[b];
    uint32_t n = be - bs;
    uint32_t csz = (n + CHUNKS - 1) / CHUNKS;
    uint32_t cs = bs + (uint32_t)c * csz;
    uint32_t ce = min(cs + csz, be);

    if (tid < FB) h[tid] = 0;
    __syncthreads();
    for (uint32_t j = cs + tid; j < ce; j += 256)
        atomicAdd(&h[key[j]], 1u);
    __syncthreads();
    if (tid < FB) chist[((uint32_t)blockIdx.x << 6) + tid] = h[tid];
}

// ---- fineB: run bases per (bucket,chunk,fine) + fine-bin starts ----
__global__ __launch_bounds__(64) void fineB_kernel(
    const uint32_t* __restrict__ chist, const uint32_t* __restrict__ cursor,
    uint32_t* __restrict__ cbase, uint32_t* __restrict__ sstart)
{
    int b = blockIdx.x;
    int f = threadIdx.x;
    uint32_t bs = b ? cursor[b - 1] : 0u;

    uint32_t cnt[CHUNKS];
    uint32_t tot = 0;
#pragma unroll
    for (int c = 0; c < CHUNKS; ++c) {
        cnt[c] = chist[(((uint32_t)b * CHUNKS + c) << 6) + f];
        tot += cnt[c];
    }
    uint32_t inc = tot;
    for (int off = 1; off < 64; off <<= 1) {
        uint32_t n = __shfl_up(inc, off);
        if (f >= off) inc += n;
    }
    uint32_t fbase = bs + inc - tot;
    sstart[((uint32_t)b << 6) + f] = fbase;
    uint32_t run = fbase;
#pragma unroll
    for (int c = 0; c < CHUNKS; ++c) {
        cbase[(((uint32_t)b * CHUNKS + c) << 6) + f] = run;
        run += cnt[c];
    }
}

// ---- fineC: stage by key, coalesced scatter into fine-bin order ----
__global__ __launch_bounds__(256) void fineC_kernel(
    const float4* __restrict__ sorted, const uint8_t* __restrict__ key,
    const uint32_t* __restrict__ cursor, const uint32_t* __restrict__ chist,
    const uint32_t* __restrict__ cbase, float4* __restrict__ sorted2)
{
    __shared__ float4 staged[CMAX];         // 40 KB
    __shared__ uint32_t lbase[FB], lcur[FB], gb[FB];
    int tid = threadIdx.x;
    int b = blockIdx.x >> 4, c = blockIdx.x & (CHUNKS - 1);
    uint32_t bs = b ? cursor[b - 1] : 0u;
    uint32_t be = cursor[b];
    uint32_t n = be - bs;
    uint32_t csz = (n + CHUNKS - 1) / CHUNKS;
    uint32_t cs = bs + (uint32_t)c * csz;
    uint32_t ce = min(cs + csz, be);
    if (ce <= cs) return;
    uint32_t m = ce - cs;

    if (tid < FB) {
        uint32_t v = chist[(((uint32_t)b * CHUNKS + c) << 6) + tid];
        uint32_t inc = v;
        for (int off = 1; off < 64; off <<= 1) {
            uint32_t nn = __shfl_up(inc, off);
            if (tid >= off) inc += nn;
        }
        lbase[tid] = inc - v;
        lcur[tid] = inc - v;
        gb[tid] = cbase[(((uint32_t)b * CHUNKS + c) << 6) + tid];
    }
    __syncthreads();

    for (uint32_t j = cs + tid; j < ce; j += 256) {
        float4 s = sorted[j];
        uint32_t slot = atomicAdd(&lcur[key[j]], 1u);
        staged[slot] = s;
    }
    __syncthreads();

    for (uint32_t j = tid; j < m; j += 256) {
        float4 s = staged[j];
        uint32_t f = fine_of(s.x, s.y, s.z);
        sorted2[gb[f] + (j - lbase[f])] = s;
    }
}

// ---- K4: block-per-16^3-superregion, 4913 LDS corners ----
// Superregion r = b*8+g spans fine bins [r*8, (r+1)*8) in global order.
__global__ __launch_bounds__(1024) void interp_super16_kernel(
    const float4* __restrict__ sorted2, const uint32_t* __restrict__ sstart,
    const float* __restrict__ table, float4* __restrict__ out4, int batch)
{
    __shared__ float4 corners[NCORN];        // 78.6 KB
    int bid = blockIdx.x;
    int swz = (bid & 7) * (NSUP16 >> 3) + (bid >> 3);   // XCD-chunked
    int tid = threadIdx.x;
    uint32_t r = (uint32_t)swz;
    uint32_t start = sstart[r << 3];
    uint32_t end = (r == NSUP16 - 1) ? (uint32_t)batch : sstart[(r + 1) << 3];
    if (start >= end) return;                // uniform exit

    // base cell: bucket bits -> cell[6:5], group bit -> cell[4]
    uint32_t b = r >> 3, g = r & 7u;
    int rbx = (int)((((b >> 4) & 3u) << 5) | (((g >> 2) & 1u) << 4));
    int rby = (int)((((b >> 2) & 3u) << 5) | (((g >> 1) & 1u) << 4));
    int rbz = (int)(((b & 3u) << 5) | ((g & 1u) << 4));

    for (int idx = tid; idx < NCORN; idx += 1024) {
        int ci = idx / 289;
        int rem = idx - ci * 289;
        int cj = rem / 17;
        int ck = rem - cj * 17;
        uint32_t h = ((uint32_t)(rbx + ci) ^
                      (uint32_t)(rby + cj) * P1 ^
                      (uint32_t)(rbz + ck) * P2) & HASH_MASK;
        corners[idx] = *reinterpret_cast<const float4*>(table + (size_t)h * 4);
    }
    __syncthreads();

    const float inv = 1.0f / 128.0f;
    for (uint32_t p = start + tid; p < end; p += 1024) {
        float4 s = sorted2[p];
        float px = s.x, py = s.y, pz = s.z;
        int lx = (int)floorf(px * 128.0f);
        int ly = (int)floorf(py * 128.0f);
        int lz = (int)floorf(pz * 128.0f);
        float w0x = (px - (float)lx * inv) * 128.0f;
        float w1x = ((float)(lx + 1) * inv - px) * 128.0f;
        float w0y = (py - (float)ly * inv) * 128.0f;
        float w1y = ((float)(ly + 1) * inv - py) * 128.0f;
        float w0z = (pz - (float)lz * inv) * 128.0f;
        float w1z = ((float)(lz + 1) * inv - pz) * 128.0f;
        int li = lx - rbx, lj = ly - rby, lk = lz - rbz;   // in [0,15]
        int cb = li * 289 + lj * 17 + lk;

        float acc0 = 0.f, acc1 = 0.f, acc2 = 0.f, acc3 = 0.f;
#pragma unroll
        for (int c8 = 0; c8 < 8; ++c8) {
            int bx = (c8 >> 2) & 1, by = (c8 >> 1) & 1, bz = c8 & 1;
            float4 v = corners[cb + bx * 289 + by * 17 + bz];
            float w = ((bx ? w1x : w0x) * (by ? w1y : w0y)) * (bz ? w1z : w0z);
            acc0 += v.x * w; acc1 += v.y * w; acc2 += v.z * w; acc3 += v.w * w;
        }
        out4[__float_as_uint(s.w)] = make_float4(acc0, acc1, acc2, acc3);
    }
}

// ---- fallback ----
__global__ __launch_bounds__(256) void interp_direct_kernel(
    const float* __restrict__ pos, const float* __restrict__ table,
    float4* __restrict__ out4, int batch)
{
    int i = blockIdx.x * 256 + threadIdx.x;
    if (i >= batch) return;
    out4[i] = interp_point(pos[3 * (size_t)i], pos[3 * (size_t)i + 1],
                           pos[3 * (size_t)i + 2], table);
}

extern "C" void kernel_launch(void* const* d_in, const int* in_sizes, int n_in,
                              void* d_out, int out_size, void* d_ws, size_t ws_size,
                              hipStream_t stream) {
    const float* pos   = (const float*)d_in[0];   // (2^21, 3)
    const float* table = (const float*)d_in[1];   // (2^22, 4)
    float4* out4 = (float4*)d_out;                // (2^21, 4)

    int batch = in_sizes[0] / 3;                  // 2^21
    int blocks256 = (batch + 255) / 256;          // 8192

    size_t sorted_off  = 512;
    size_t sorted2_off = sorted_off + (size_t)batch * 16;
    size_t chist_off   = sorted2_off + (size_t)batch * 16;
    size_t chist_bytes = (size_t)NBUCK * CHUNKS * FB * 4;     // 256 KB
    size_t cbase_off   = chist_off + chist_bytes;
    size_t sstart_off  = cbase_off + chist_bytes;
    size_t key_off     = sstart_off + (size_t)NBUCK * FB * 4;
    size_t need_full   = key_off + (size_t)batch;

    bool exact = (batch % PPB == 0) && ((blocks256 & 7) == 0);
    if (ws_size < need_full || !exact) {
        interp_direct_kernel<<<blocks256, 256, 0, stream>>>(pos, table, out4, batch);
        return;
    }

    uint32_t* hist    = (uint32_t*)d_ws;
    uint32_t* cursor  = (uint32_t*)((char*)d_ws + 256);
    float4*   sorted  = (float4*)((char*)d_ws + sorted_off);
    float4*   sorted2 = (float4*)((char*)d_ws + sorted2_off);
    uint32_t* chist   = (uint32_t*)((char*)d_ws + chist_off);
    uint32_t* cbase   = (uint32_t*)((char*)d_ws + cbase_off);
    uint32_t* sstart  = (uint32_t*)((char*)d_ws + sstart_off);
    uint8_t*  key     = (uint8_t*)((char*)d_ws + key_off);

    int sblocks = batch / PPB;                    // 512

    hipMemsetAsync(hist, 0, NBUCK * sizeof(uint32_t), stream);
    hist_kernel<<<sblocks, K3_BLOCK, 0, stream>>>(pos, hist, batch);
    scan_kernel<<<1, 64, 0, stream>>>(hist, cursor);
    scatter_kernel<<<sblocks, K3_BLOCK, 0, stream>>>(pos, cursor, sorted, key, batch);
    fineA_kernel<<<NBUCK * CHUNKS, 256, 0, stream>>>(key, cursor, chist);
    fineB_kernel<<<NBUCK, 64, 0, stream>>>(chist, cursor, cbase, sstart);
    fineC_kernel<<<NBUCK * CHUNKS, 256, 0, stream>>>(sorted, key, cursor, chist,
                                                     cbase, sorted2);
    interp_super16_kernel<<<NSUP16, 1024, 0, stream>>>(sorted2, sstart, table,
                                                       out4, batch);
}

// Round 15
// 106.749 us; speedup vs baseline: 1.0291x; 1.0291x over previous
//
#include <hip/hip_runtime.h>
#include <stdint.h>

// HashedInterpolator R14 = R9 verbatim (best measured: 106.9 us).
// Pipeline: K1 hist64 -> K2 scan64 -> K3 bucket scatter (+key) ->
// fineA (chist from key) -> fineB (cbase+sstart) -> fineC (sorted2) ->
// K4 block-per-8^3-superregion (729 LDS corners), scatter to out[orig].
// Structural floor: ~134MB distinct random corner lines + ~160MB sort streams
// + ~67MB scattered out-write RMW at ~3.5-5 TB/s fabric => ~100 us.

#define HASH_MASK 0x3FFFFFu
#define P1 19349663u
#define P2 83492791u
#define NBUCK 64
#define CHUNKS 16
#define FB 64                     // fine bins per bucket = 8^3 superregions
#define NSUP 4096                 // total superregions
#define PPT 16
#define K3_BLOCK 256
#define PPB (K3_BLOCK * PPT)      // 4096 points per block
#define CMAX 2560                 // max chunk size staged in fineC (40KB LDS)

__device__ __forceinline__ uint32_t bucket_of(float px, float py, float pz) {
    uint32_t bx = ((uint32_t)(int)floorf(px * 128.0f)) >> 5;
    uint32_t by = ((uint32_t)(int)floorf(py * 128.0f)) >> 5;
    uint32_t bz = ((uint32_t)(int)floorf(pz * 128.0f)) >> 5;
    return (bx << 4) | (by << 2) | bz;
}

__device__ __forceinline__ uint32_t spread3(uint32_t v) {
    return (v & 1u) | ((v & 2u) << 2) | ((v & 4u) << 4);
}

// fine bin within bucket: region coord = (cell>>2) & 7 per axis, Morton-coded
__device__ __forceinline__ uint32_t fine_bin(float px, float py, float pz) {
    uint32_t cx = (((uint32_t)(int)floorf(px * 128.0f)) >> 2) & 7u;
    uint32_t cy = (((uint32_t)(int)floorf(py * 128.0f)) >> 2) & 7u;
    uint32_t cz = (((uint32_t)(int)floorf(pz * 128.0f)) >> 2) & 7u;
    return (spread3(cx) << 2) | (spread3(cy) << 1) | spread3(cz);
}

// fine bin for K3/fineA/fineC (same mapping as R9: (fx<<4)|(fy<<2)|fz)
__device__ __forceinline__ uint32_t fine_of(float px, float py, float pz) {
    uint32_t fx = (((uint32_t)(int)floorf(px * 128.0f)) >> 3) & 3u;
    uint32_t fy = (((uint32_t)(int)floorf(py * 128.0f)) >> 3) & 3u;
    uint32_t fz = (((uint32_t)(int)floorf(pz * 128.0f)) >> 3) & 3u;
    return (fx << 4) | (fy << 2) | fz;
}

__device__ __forceinline__ float4 interp_point(float px, float py, float pz,
                                               const float* __restrict__ table) {
    int lx = (int)floorf(px * 128.0f);
    int ly = (int)floorf(py * 128.0f);
    int lz = (int)floorf(pz * 128.0f);
    const float inv = 1.0f / 128.0f;
    float w0x = (px - (float)lx * inv) * 128.0f;
    float w1x = ((float)(lx + 1) * inv - px) * 128.0f;
    float w0y = (py - (float)ly * inv) * 128.0f;
    float w1y = ((float)(ly + 1) * inv - py) * 128.0f;
    float w0z = (pz - (float)lz * inv) * 128.0f;
    float w1z = ((float)(lz + 1) * inv - pz) * 128.0f;
    uint32_t hx0 = (uint32_t)lx, hx1 = (uint32_t)(lx + 1);
    uint32_t hy0 = (uint32_t)ly * P1, hy1 = (uint32_t)(ly + 1) * P1;
    uint32_t hz0 = (uint32_t)lz * P2, hz1 = (uint32_t)(lz + 1) * P2;
    float acc0 = 0.f, acc1 = 0.f, acc2 = 0.f, acc3 = 0.f;
#pragma unroll
    for (int c = 0; c < 8; ++c) {
        int bx = (c >> 2) & 1, by = (c >> 1) & 1, bz = c & 1;
        uint32_t h = ((bx ? hx1 : hx0) ^ (by ? hy1 : hy0) ^ (bz ? hz1 : hz0)) & HASH_MASK;
        const float4 v = *reinterpret_cast<const float4*>(table + (size_t)h * 4);
        float w = ((bx ? w1x : w0x) * (by ? w1y : w0y)) * (bz ? w1z : w0z);
        acc0 += v.x * w; acc1 += v.y * w; acc2 += v.z * w; acc3 += v.w * w;
    }
    return make_float4(acc0, acc1, acc2, acc3);
}

// ---- K1: per-block LDS histogram (64 bins) ----
__global__ __launch_bounds__(K3_BLOCK) void hist_kernel(
    const float* __restrict__ pos, uint32_t* __restrict__ hist, int batch)
{
    __shared__ uint32_t h[NBUCK];
    int tid = threadIdx.x;
    size_t start = (size_t)blockIdx.x * PPB;
    if (tid < NBUCK) h[tid] = 0;
    __syncthreads();
#pragma unroll
    for (int k = 0; k < PPT; ++k) {
        size_t i = start + (size_t)k * K3_BLOCK + tid;
        if (i < (size_t)batch) {
            float px = pos[3 * i + 0];
            float py = pos[3 * i + 1];
            float pz = pos[3 * i + 2];
            atomicAdd(&h[bucket_of(px, py, pz)], 1u);
        }
    }
    __syncthreads();
    if (tid < NBUCK && h[tid]) atomicAdd(&hist[tid], h[tid]);
}

// ---- K2: 64-bin exclusive scan ----
__global__ __launch_bounds__(64) void scan_kernel(
    const uint32_t* __restrict__ hist, uint32_t* __restrict__ cursor)
{
    int t = threadIdx.x;
    uint32_t v = hist[t];
    uint32_t inc = v;
    for (int off = 1; off < 64; off <<= 1) {
        uint32_t n = __shfl_up(inc, off);
        if (t >= off) inc += n;
    }
    cursor[t] = inc - v;
}

// ---- K3: LDS-staged coarse scatter (coalesced) + key emission ----
__global__ __launch_bounds__(K3_BLOCK) void scatter_kernel(
    const float* __restrict__ pos, uint32_t* __restrict__ cursor,
    float4* __restrict__ sorted, uint8_t* __restrict__ key, int batch)
{
    __shared__ float4 staged[PPB];
    __shared__ uint32_t h[NBUCK], lbase[NBUCK], gbase[NBUCK], lcur[NBUCK];
    int tid = threadIdx.x;
    size_t start = (size_t)blockIdx.x * PPB;

    if (tid < NBUCK) h[tid] = 0;
    __syncthreads();

    float px[PPT], py[PPT], pz[PPT];
    uint32_t bb[PPT];
#pragma unroll
    for (int k = 0; k < PPT; ++k) {
        size_t i = start + (size_t)k * K3_BLOCK + tid;
        px[k] = pos[3 * i + 0];
        py[k] = pos[3 * i + 1];
        pz[k] = pos[3 * i + 2];
        bb[k] = bucket_of(px[k], py[k], pz[k]);
        atomicAdd(&h[bb[k]], 1u);
    }
    __syncthreads();

    if (tid < NBUCK) {
        uint32_t v = h[tid];
        uint32_t inc = v;
        for (int off = 1; off < 64; off <<= 1) {
            uint32_t n = __shfl_up(inc, off);
            if (tid >= off) inc += n;
        }
        uint32_t excl = inc - v;
        lbase[tid] = excl;
        lcur[tid] = excl;
        gbase[tid] = atomicAdd(&cursor[tid], v);
    }
    __syncthreads();

#pragma unroll
    for (int k = 0; k < PPT; ++k) {
        size_t i = start + (size_t)k * K3_BLOCK + tid;
        uint32_t slot = atomicAdd(&lcur[bb[k]], 1u);
        staged[slot] = make_float4(px[k], py[k], pz[k], __uint_as_float((uint32_t)i));
    }
    __syncthreads();

#pragma unroll
    for (int k = 0; k < PPT; ++k) {
        int j = k * K3_BLOCK + tid;
        float4 s = staged[j];
        uint32_t b = bucket_of(s.x, s.y, s.z);
        uint32_t slot = gbase[b] + ((uint32_t)j - lbase[b]);
        sorted[slot] = s;
        key[slot] = (uint8_t)fine_of(s.x, s.y, s.z);
    }
}

// ---- fineA: per (bucket,chunk) 64-bin histogram from key bytes ----
__global__ __launch_bounds__(256) void fineA_kernel(
    const uint8_t* __restrict__ key, const uint32_t* __restrict__ cursor,
    uint32_t* __restrict__ chist)
{
    __shared__ uint32_t h[FB];
    int tid = threadIdx.x;
    int b = blockIdx.x >> 4, c = blockIdx.x & (CHUNKS - 1);
    uint32_t bs = b ? cursor[b - 1] : 0u;
    uint32_t be = cursor[b];
    uint32_t n = be - bs;
    uint32_t csz = (n + CHUNKS - 1) / CHUNKS;
    uint32_t cs = bs + (uint32_t)c * csz;
    uint32_t ce = min(cs + csz, be);

    if (tid < FB) h[tid] = 0;
    __syncthreads();
    for (uint32_t j = cs + tid; j < ce; j += 256)
        atomicAdd(&h[key[j]], 1u);
    __syncthreads();
    if (tid < FB) chist[((uint32_t)blockIdx.x << 6) + tid] = h[tid];
}

// ---- fineB: run bases per (bucket,chunk,fine) + superregion starts ----
__global__ __launch_bounds__(64) void fineB_kernel(
    const uint32_t* __restrict__ chist, const uint32_t* __restrict__ cursor,
    uint32_t* __restrict__ cbase, uint32_t* __restrict__ sstart)
{
    int b = blockIdx.x;
    int f = threadIdx.x;
    uint32_t bs = b ? cursor[b - 1] : 0u;

    uint32_t cnt[CHUNKS];
    uint32_t tot = 0;
#pragma unroll
    for (int c = 0; c < CHUNKS; ++c) {
        cnt[c] = chist[(((uint32_t)b * CHUNKS + c) << 6) + f];
        tot += cnt[c];
    }
    uint32_t inc = tot;
    for (int off = 1; off < 64; off <<= 1) {
        uint32_t n = __shfl_up(inc, off);
        if (f >= off) inc += n;
    }
    uint32_t fbase = bs + inc - tot;
    sstart[((uint32_t)b << 6) + f] = fbase;
    uint32_t run = fbase;
#pragma unroll
    for (int c = 0; c < CHUNKS; ++c) {
        cbase[(((uint32_t)b * CHUNKS + c) << 6) + f] = run;
        run += cnt[c];
    }
}

// ---- fineC: stage by key, coalesced scatter into superregion order ----
__global__ __launch_bounds__(256) void fineC_kernel(
    const float4* __restrict__ sorted, const uint8_t* __restrict__ key,
    const uint32_t* __restrict__ cursor, const uint32_t* __restrict__ chist,
    const uint32_t* __restrict__ cbase, float4* __restrict__ sorted2)
{
    __shared__ float4 staged[CMAX];         // 40 KB
    __shared__ uint32_t lbase[FB], lcur[FB], gb[FB];
    int tid = threadIdx.x;
    int b = blockIdx.x >> 4, c = blockIdx.x & (CHUNKS - 1);
    uint32_t bs = b ? cursor[b - 1] : 0u;
    uint32_t be = cursor[b];
    uint32_t n = be - bs;
    uint32_t csz = (n + CHUNKS - 1) / CHUNKS;
    uint32_t cs = bs + (uint32_t)c * csz;
    uint32_t ce = min(cs + csz, be);
    if (ce <= cs) return;
    uint32_t m = ce - cs;

    if (tid < FB) {
        uint32_t v = chist[(((uint32_t)b * CHUNKS + c) << 6) + tid];
        uint32_t inc = v;
        for (int off = 1; off < 64; off <<= 1) {
            uint32_t nn = __shfl_up(inc, off);
            if (tid >= off) inc += nn;
        }
        lbase[tid] = inc - v;
        lcur[tid] = inc - v;
        gb[tid] = cbase[(((uint32_t)b * CHUNKS + c) << 6) + tid];
    }
    __syncthreads();

    for (uint32_t j = cs + tid; j < ce; j += 256) {
        float4 s = sorted[j];
        uint32_t slot = atomicAdd(&lcur[key[j]], 1u);
        staged[slot] = s;
    }
    __syncthreads();

    for (uint32_t j = tid; j < m; j += 256) {
        float4 s = staged[j];
        uint32_t f = fine_of(s.x, s.y, s.z);
        sorted2[gb[f] + (j - lbase[f])] = s;
    }
}

// ---- K4: block-per-superregion, 729 LDS corners, scatter to out[orig] ----
__global__ __launch_bounds__(256) void interp_super_kernel(
    const float4* __restrict__ sorted2, const uint32_t* __restrict__ sstart,
    const float* __restrict__ table, float4* __restrict__ out4, int batch)
{
    __shared__ float4 corners[729];          // 11.7 KB, block-shared
    int bid = blockIdx.x;
    int swz = (bid & 7) * (NSUP >> 3) + (bid >> 3);   // XCD-chunked
    int tid = threadIdx.x;
    uint32_t r = (uint32_t)swz;
    uint32_t start = sstart[r];
    uint32_t end = (r == NSUP - 1) ? (uint32_t)batch : sstart[r + 1];
    if (start >= end) return;                 // uniform: no thread reaches sync

    float4 s0 = sorted2[start];
    int rbx = (((int)floorf(s0.x * 128.0f)) >> 3) << 3;
    int rby = (((int)floorf(s0.y * 128.0f)) >> 3) << 3;
    int rbz = (((int)floorf(s0.z * 128.0f)) >> 3) << 3;

    for (int idx = tid; idx < 729; idx += 256) {
        int ci = idx / 81;
        int rem = idx - ci * 81;
        int cj = rem / 9;
        int ck = rem - cj * 9;
        uint32_t h = ((uint32_t)(rbx + ci) ^
                      (uint32_t)(rby + cj) * P1 ^
                      (uint32_t)(rbz + ck) * P2) & HASH_MASK;
        corners[idx] = *reinterpret_cast<const float4*>(table + (size_t)h * 4);
    }
    __syncthreads();

    const float inv = 1.0f / 128.0f;
    for (uint32_t p = start + tid; p < end; p += 256) {
        float4 s = sorted2[p];
        float px = s.x, py = s.y, pz = s.z;
        int lx = (int)floorf(px * 128.0f);
        int ly = (int)floorf(py * 128.0f);
        int lz = (int)floorf(pz * 128.0f);
        float w0x = (px - (float)lx * inv) * 128.0f;
        float w1x = ((float)(lx + 1) * inv - px) * 128.0f;
        float w0y = (py - (float)ly * inv) * 128.0f;
        float w1y = ((float)(ly + 1) * inv - py) * 128.0f;
        float w0z = (pz - (float)lz * inv) * 128.0f;
        float w1z = ((float)(lz + 1) * inv - pz) * 128.0f;
        int li = lx - rbx, lj = ly - rby, lk = lz - rbz;   // in [0,7]
        int base = li * 81 + lj * 9 + lk;

        float acc0 = 0.f, acc1 = 0.f, acc2 = 0.f, acc3 = 0.f;
#pragma unroll
        for (int c8 = 0; c8 < 8; ++c8) {
            int bx = (c8 >> 2) & 1, by = (c8 >> 1) & 1, bz = c8 & 1;
            float4 v = corners[base + bx * 81 + by * 9 + bz];
            float w = ((bx ? w1x : w0x) * (by ? w1y : w0y)) * (bz ? w1z : w0z);
            acc0 += v.x * w; acc1 += v.y * w; acc2 += v.z * w; acc3 += v.w * w;
        }
        out4[__float_as_uint(s.w)] = make_float4(acc0, acc1, acc2, acc3);
    }
}

// ---- fallback ----
__global__ __launch_bounds__(256) void interp_direct_kernel(
    const float* __restrict__ pos, const float* __restrict__ table,
    float4* __restrict__ out4, int batch)
{
    int i = blockIdx.x * 256 + threadIdx.x;
    if (i >= batch) return;
    out4[i] = interp_point(pos[3 * (size_t)i], pos[3 * (size_t)i + 1],
                           pos[3 * (size_t)i + 2], table);
}

extern "C" void kernel_launch(void* const* d_in, const int* in_sizes, int n_in,
                              void* d_out, int out_size, void* d_ws, size_t ws_size,
                              hipStream_t stream) {
    const float* pos   = (const float*)d_in[0];   // (2^21, 3)
    const float* table = (const float*)d_in[1];   // (2^22, 4)
    float4* out4 = (float4*)d_out;                // (2^21, 4)

    int batch = in_sizes[0] / 3;                  // 2^21
    int blocks256 = (batch + 255) / 256;          // 8192

    size_t sorted_off  = 512;
    size_t sorted2_off = sorted_off + (size_t)batch * 16;
    size_t chist_off   = sorted2_off + (size_t)batch * 16;
    size_t chist_bytes = (size_t)NBUCK * CHUNKS * FB * 4;     // 256 KB
    size_t cbase_off   = chist_off + chist_bytes;
    size_t sstart_off  = cbase_off + chist_bytes;
    size_t key_off     = sstart_off + (size_t)NSUP * 4;
    size_t need_full   = key_off + (size_t)batch;

    bool exact = (batch % PPB == 0) && ((blocks256 & 7) == 0);
    if (ws_size < need_full || !exact) {
        interp_direct_kernel<<<blocks256, 256, 0, stream>>>(pos, table, out4, batch);
        return;
    }

    uint32_t* hist    = (uint32_t*)d_ws;
    uint32_t* cursor  = (uint32_t*)((char*)d_ws + 256);
    float4*   sorted  = (float4*)((char*)d_ws + sorted_off);
    float4*   sorted2 = (float4*)((char*)d_ws + sorted2_off);
    uint32_t* chist   = (uint32_t*)((char*)d_ws + chist_off);
    uint32_t* cbase   = (uint32_t*)((char*)d_ws + cbase_off);
    uint32_t* sstart  = (uint32_t*)((char*)d_ws + sstart_off);
    uint8_t*  key     = (uint8_t*)((char*)d_ws + key_off);

    int sblocks = batch / PPB;                    // 512

    hipMemsetAsync(hist, 0, NBUCK * sizeof(uint32_t), stream);
    hist_kernel<<<sblocks, K3_BLOCK, 0, stream>>>(pos, hist, batch);
    scan_kernel<<<1, 64, 0, stream>>>(hist, cursor);
    scatter_kernel<<<sblocks, K3_BLOCK, 0, stream>>>(pos, cursor, sorted, key, batch);
    fineA_kernel<<<NBUCK * CHUNKS, 256, 0, stream>>>(key, cursor, chist);
    fineB_kernel<<<NBUCK, 64, 0, stream>>>(chist, cursor, cbase, sstart);
    fineC_kernel<<<NBUCK * CHUNKS, 256, 0, stream>>>(sorted, key, cursor, chist,
                                                     cbase, sorted2);
    interp_super_kernel<<<NSUP, 256, 0, stream>>>(sorted2, sstart, table, out4, batch);
}